// Round 4
// baseline (4552.591 us; speedup 1.0000x reference)
//
#include <hip/hip_runtime.h>
#include <hip/hip_cooperative_groups.h>

// LSTM: B=64, T=256, IN=512, H=1024 (4H=4096), OUT=512. I/O f32.
// Round-14 = round-13 (512 threads, 8 waves, split-K) with the LDS
// overflow fixed: r13 asked for 66816 B static LDS (> 64 KB limit) ->
// compile failure, never ran. Out-proj C-tile has only 8 valid batch
// rows (A rows 8..15 are zero), so obuf shrinks [8][16][17] ->
// [8][8][17] (writes guarded quad<2). New total 62464 B < 65536.
//   Theory under test (from r12 counters): ~11us/step of stall is
//   exposed LLC load latency at 1 wave/SIMD. 2 waves/SIMD + half the
//   per-wave load count should cut it ~4x.
//   - gate GEMM: wave w owns (batch-tile w&3, k-half w>>2); partials
//     in gbufp[2][64][17], summed (+bias) in phase B.
//   - out-proj: K split 8 ways (wof[4]/wave), obuf[8] partials.
//   - barrier, h publication (sc0sc1 write-through), poll, single
//     acquire fence: IDENTICAL to r12.
// Numerics identical (same MFMA tiling, same hi/lo split; bias added
// once in f32 in phase B as before -> absmax stays 7.8e-3).

#define B_   64
#define T_   256
#define IN_  512
#define H_   1024
#define G4_  4096
#define OUT_ 512
#define KTOT 1536   // IN_ + H_

typedef __bf16 bf8v  __attribute__((ext_vector_type(8)));
typedef float  f4v   __attribute__((ext_vector_type(4)));

__device__ __forceinline__ float sigm(float x) { return 1.f / (1.f + __expf(-x)); }
__device__ __forceinline__ float tanh_f(float x) { return 1.f - 2.f / (__expf(2.f * x) + 1.f); }

// Write-through store of one bf16, bypassing L1 (sc0) and L2 (sc1):
// value is visible at the LLC (agent coherence point) when vmcnt retires.
__device__ __forceinline__ void store_bf16_wt(__bf16* p, __bf16 v) {
    union { __bf16 b; unsigned short s; } cv; cv.b = v;
    unsigned w = cv.s;
    asm volatile("global_store_short %0, %1, off sc0 sc1"
                 :: "v"(p), "v"(w) : "memory");
}

// Flag-vector all-block barrier. flags[i*16] (64B apart), monotonic.
// t-th use: every flag reaches t+1. Arrival = one independent
// write-through store; wait = wave-0 polls all 256 flags directly.
__device__ __forceinline__ void grid_barrier(unsigned* flags, int t, int blk) {
    __syncthreads();   // drains vmcnt: all waves' sc0sc1 h stores ack'd at LLC
    const unsigned tgt = (unsigned)(t + 1);
    if (threadIdx.x < 64) {
        if (threadIdx.x == 0) {
            unsigned* p = &flags[blk * 16];
            asm volatile("global_store_dword %0, %1, off sc0 sc1"
                         :: "v"(p), "v"(tgt) : "memory");
        }
        const int lane = threadIdx.x;
        for (;;) {
            unsigned m0 = __hip_atomic_load(&flags[(lane * 4 + 0) * 16],
                                            __ATOMIC_RELAXED, __HIP_MEMORY_SCOPE_AGENT);
            unsigned m1 = __hip_atomic_load(&flags[(lane * 4 + 1) * 16],
                                            __ATOMIC_RELAXED, __HIP_MEMORY_SCOPE_AGENT);
            unsigned m2 = __hip_atomic_load(&flags[(lane * 4 + 2) * 16],
                                            __ATOMIC_RELAXED, __HIP_MEMORY_SCOPE_AGENT);
            unsigned m3 = __hip_atomic_load(&flags[(lane * 4 + 3) * 16],
                                            __ATOMIC_RELAXED, __HIP_MEMORY_SCOPE_AGENT);
            bool ok = (m0 >= tgt) & (m1 >= tgt) & (m2 >= tgt) & (m3 >= tgt);
            if (__all(ok)) break;
            __builtin_amdgcn_s_sleep(1);   // ~64cy backoff: cut LLC poll pressure
        }
        __builtin_amdgcn_fence(__ATOMIC_ACQUIRE, "agent");   // one inv: h visible to cached loads
    }
    __syncthreads();
}

__global__ void __launch_bounds__(512)
lstm_fused(const float* __restrict__ xs, const float* __restrict__ Wi,
           const float* __restrict__ Wh, const float* __restrict__ bias,
           const float* __restrict__ Wo, const float* __restrict__ bo,
           float* __restrict__ out, __bf16* __restrict__ hws,
           unsigned* __restrict__ flags)
{
    __shared__ __bf16 Wlds[16][KTOT + 8];   // 49408 B (bf16-rounded weights)
    __shared__ float  gbufp[2][64][17];     // 8704 B  (gate partials, k-halves)
    __shared__ float  obuf[8][8][17];       // 4352 B  (out-proj partials, 8 valid rows)
                                            // total 62464 B < 65536

    const int tid = threadIdx.x;
    const int blk = blockIdx.x;       // 0..255
    const int j0  = blk * 4;
    const int ob0 = (blk >> 5) * 8;   // out-proj batch group (8 batches)
    const int oc0 = (blk & 31) * 16;  // out-proj col group (16 cols)

    // Stage resident gate-weight slab (f32 -> bf16)
    for (int idx = tid; idx < 16 * KTOT; idx += 512) {
        int k = idx >> 4, c = idx & 15;
        int gc = (c >> 2) * H_ + j0 + (c & 3);
        float w = (k < IN_) ? Wi[(size_t)k * G4_ + gc]
                            : Wh[(size_t)(k - IN_) * G4_ + gc];
        Wlds[c][k] = (__bf16)w;
    }
    __syncthreads();

    const int lane = tid & 63;
    const int wave = tid >> 6;        // 0..7
    const int c    = lane & 15;
    const int quad = lane >> 4;
    const int wg   = wave & 3;        // batch tile (16 rows)
    const int kh   = wave >> 2;       // k-half
    const int rowA = wg * 16 + c;     // batch row for gate A-frags
    const int kq   = quad * 8;

    // Hoist step-invariant Wo fragments into registers (f32 -> bf16).
    // Wave w owns out-proj K range [w*128, w*128+128).
    bf8v wof[4];
    #pragma unroll
    for (int kk = 0; kk < 4; ++kk) {
        int kbase = wave * 128 + kk * 32 + kq;
        #pragma unroll
        for (int j = 0; j < 8; ++j)
            wof[kk][j] = (__bf16)Wo[(size_t)(kbase + j) * OUT_ + oc0 + c];
    }

    // recurrent cell state: thread (tid<256) owns (batch = tid>>2, j = j0+(tid&3))
    float c_reg = 0.f;
    const int bb = tid >> 2;
    const int jo = tid & 3;
    float bi0 = 0.f, bi1 = 0.f, bi2 = 0.f, bi3 = 0.f;
    if (tid < 256) {
        bi0 = bias[0 * H_ + j0 + jo];
        bi1 = bias[1 * H_ + j0 + jo];
        bi2 = bias[2 * H_ + j0 + jo];
        bi3 = bias[3 * H_ + j0 + jo];
    }

    // h ws layout: [buf(2)][part hi/lo][B][H] bf16
    for (int t = 0; t < T_; ++t) {
        const __bf16* hhi_p = hws + (size_t)(t & 1) * (2 * B_ * H_);
        const __bf16* hlo_p = hhi_p + B_ * H_;
        __bf16* hhi_c = hws + (size_t)((t + 1) & 1) * (2 * B_ * H_);
        __bf16* hlo_c = hhi_c + B_ * H_;

        // ---- phase A: gate MFMA for step t (this wave's k-half) ----
        f4v acc0 = {0.f, 0.f, 0.f, 0.f};   // hi-product chain
        f4v acc1 = {0.f, 0.f, 0.f, 0.f};   // lo-product chain
        const float* xrow = xs + ((size_t)rowA * T_ + t) * IN_ + kh * 256 + kq;
        #pragma unroll
        for (int ks = 0; ks < 8; ++ks) {
            f4v v0 = *(const f4v*)(xrow + ks * 32);
            f4v v1 = *(const f4v*)(xrow + ks * 32 + 4);
            bf8v ah, al;
            #pragma unroll
            for (int j = 0; j < 4; ++j) {
                __bf16 h0 = (__bf16)v0[j], h1 = (__bf16)v1[j];
                ah[j] = h0;  ah[4 + j] = h1;
                al[j]     = (__bf16)(v0[j] - (float)h0);
                al[4 + j] = (__bf16)(v1[j] - (float)h1);
            }
            bf8v w = *(const bf8v*)&Wlds[c][kh * 256 + ks * 32 + kq];
            acc0 = __builtin_amdgcn_mfma_f32_16x16x32_bf16(ah, w, acc0, 0, 0, 0);
            acc1 = __builtin_amdgcn_mfma_f32_16x16x32_bf16(al, w, acc1, 0, 0, 0);
        }
        if (t > 0) {
            const __bf16* hh = hhi_p + (size_t)rowA * H_ + kh * 512 + kq;
            const __bf16* hl = hlo_p + (size_t)rowA * H_ + kh * 512 + kq;
            #pragma unroll
            for (int ks = 0; ks < 16; ++ks) {
                bf8v ah = *(const bf8v*)(hh + ks * 32);
                bf8v al = *(const bf8v*)(hl + ks * 32);
                bf8v w  = *(const bf8v*)&Wlds[c][IN_ + kh * 512 + ks * 32 + kq];
                acc0 = __builtin_amdgcn_mfma_f32_16x16x32_bf16(ah, w, acc0, 0, 0, 0);
                acc1 = __builtin_amdgcn_mfma_f32_16x16x32_bf16(al, w, acc1, 0, 0, 0);
            }
        }
        f4v acc = acc0 + acc1;
        #pragma unroll
        for (int r = 0; r < 4; ++r)
            gbufp[kh][wg * 16 + quad * 4 + r][c] = acc[r];   // partial, no bias yet

        // ---- phase A2: out-proj partial for step t-1 (reads same h_{t-1}) ----
        if (t > 0) {
            f4v oac = {0.f, 0.f, 0.f, 0.f};
            #pragma unroll
            for (int kk = 0; kk < 4; ++kk) {
                int kbase = wave * 128 + kk * 32 + kq;
                bf8v ah = {}, al = {};
                if (c < 8) {   // A rows 8..15 zero (8 batches per tile)
                    ah = *(const bf8v*)&hhi_p[(size_t)(ob0 + c) * H_ + kbase];
                    al = *(const bf8v*)&hlo_p[(size_t)(ob0 + c) * H_ + kbase];
                }
                oac = __builtin_amdgcn_mfma_f32_16x16x32_bf16(ah, wof[kk], oac, 0, 0, 0);
                oac = __builtin_amdgcn_mfma_f32_16x16x32_bf16(al, wof[kk], oac, 0, 0, 0);
            }
            if (quad < 2) {   // C rows 0..7 are the valid batches
                #pragma unroll
                for (int r = 0; r < 4; ++r)
                    obuf[wave][quad * 4 + r][c] = oac[r];
            }
        }
        __syncthreads();

        // ---- phase B: elementwise cell update, write h_t (hi+lo, write-through) ----
        if (tid < 256) {
            float gi = gbufp[0][bb][jo]      + gbufp[1][bb][jo]      + bi0;
            float gf = gbufp[0][bb][4 + jo]  + gbufp[1][bb][4 + jo]  + bi1;
            float gg = gbufp[0][bb][8 + jo]  + gbufp[1][bb][8 + jo]  + bi2;
            float go = gbufp[0][bb][12 + jo] + gbufp[1][bb][12 + jo] + bi3;
            c_reg = sigm(gf) * c_reg + sigm(gi) * tanh_f(gg);
            float hn = sigm(go) * tanh_f(c_reg);
            __bf16 hh = (__bf16)hn;
            store_bf16_wt(&hhi_c[(size_t)bb * H_ + j0 + jo], hh);
            store_bf16_wt(&hlo_c[(size_t)bb * H_ + j0 + jo], (__bf16)(hn - (float)hh));
        }
        // ---- phase B2: reduce out-proj partials, store out[:, t-1, :] ----
        if (t > 0 && tid < 128) {
            int m = tid >> 4, cc = tid & 15;
            float v = obuf[0][m][cc] + obuf[1][m][cc] + obuf[2][m][cc] + obuf[3][m][cc]
                    + obuf[4][m][cc] + obuf[5][m][cc] + obuf[6][m][cc] + obuf[7][m][cc]
                    + bo[oc0 + cc];
            out[(((size_t)(ob0 + m)) * T_ + (t - 1)) * OUT_ + oc0 + cc] = v;
        }

        grid_barrier(flags, t, blk);   // publish h_t; guards gbufp/obuf WAR
    }

    // ---- epilogue: out-proj for t = T-1 (h_{T-1} is in buffer 0; T even) ----
    {
        const __bf16* hhi_l = hws;
        const __bf16* hlo_l = hws + B_ * H_;
        f4v oac = {0.f, 0.f, 0.f, 0.f};
        #pragma unroll
        for (int kk = 0; kk < 4; ++kk) {
            int kbase = wave * 128 + kk * 32 + kq;
            bf8v ah = {}, al = {};
            if (c < 8) {
                ah = *(const bf8v*)&hhi_l[(size_t)(ob0 + c) * H_ + kbase];
                al = *(const bf8v*)&hlo_l[(size_t)(ob0 + c) * H_ + kbase];
            }
            oac = __builtin_amdgcn_mfma_f32_16x16x32_bf16(ah, wof[kk], oac, 0, 0, 0);
            oac = __builtin_amdgcn_mfma_f32_16x16x32_bf16(al, wof[kk], oac, 0, 0, 0);
        }
        if (quad < 2) {
            #pragma unroll
            for (int r = 0; r < 4; ++r)
                obuf[wave][quad * 4 + r][c] = oac[r];
        }
        __syncthreads();
        if (tid < 128) {
            int m = tid >> 4, cc = tid & 15;
            float v = obuf[0][m][cc] + obuf[1][m][cc] + obuf[2][m][cc] + obuf[3][m][cc]
                    + obuf[4][m][cc] + obuf[5][m][cc] + obuf[6][m][cc] + obuf[7][m][cc]
                    + bo[oc0 + cc];
            out[(((size_t)(ob0 + m)) * T_ + (T_ - 1)) * OUT_ + oc0 + cc] = v;
        }
    }
}

extern "C" void kernel_launch(void* const* d_in, const int* in_sizes, int n_in,
                              void* d_out, int out_size, void* d_ws, size_t ws_size,
                              hipStream_t stream) {
    const float* xs = (const float*)d_in[0];
    const float* Wi = (const float*)d_in[1];
    const float* Wh = (const float*)d_in[2];
    const float* b  = (const float*)d_in[3];
    const float* Wo = (const float*)d_in[4];
    const float* bo = (const float*)d_in[5];
    float* out = (float*)d_out;

    // ws layout: [0,16K) flag vector (256 x 64B-padded, zeroed);
    //            [64K, +512K) h double-buffer (hi/lo bf16)
    unsigned* flags = (unsigned*)d_ws;         // flags[i*16], i = 0..255
    __bf16*   hws   = (__bf16*)((char*)d_ws + 65536);

    hipMemsetAsync(d_ws, 0, 32768, stream);    // reset flags (graph-capture safe)

    void* args[] = {(void*)&xs, (void*)&Wi, (void*)&Wh, (void*)&b,
                    (void*)&Wo, (void*)&bo, (void*)&out, (void*)&hws,
                    (void*)&flags};
    hipLaunchCooperativeKernel((void*)lstm_fused, dim3(256), dim3(512), args, 0, stream);
}